// Round 1
// baseline (485.334 us; speedup 1.0000x reference)
//
#include <hip/hip_runtime.h>
#include <hip/hip_bf16.h>

// MoE gate: logits = x(T,4096) @ W(64,4096)^T ; softmax ; group-limited top-k.
// T = 16384, E = 64, H = 4096, groups = 8x8, topk_group = 3, top_k = 6.
// Outputs (concatenated in d_out, all as float32): idx[T*6] (float-encoded ints),
// weight[T*6], both sorted descending by weight with jax top_k tie-breaking.

#define TM     32    // tokens per block
#define HK     128   // K-chunk staged in LDS
#define PITCH  132   // LDS row pitch in floats (pad 4 -> 2-way max aliasing)
#define NE     64
#define NH     4096
#define NTOPK  6

__global__ __launch_bounds__(256, 2) void moe_gate_kernel(
    const float* __restrict__ x, const float* __restrict__ w,
    float* __restrict__ out_idx, float* __restrict__ out_w)
{
    __shared__ float xs[TM * PITCH];   // 16.9 KB
    __shared__ float ws[NE * PITCH];   // 33.8 KB

    const int tid = threadIdx.x;
    const int tx  = tid & 15;          // expert-dim thread coord (16)
    const int ty  = tid >> 4;          // token-dim thread coord (16)
    const int t0  = blockIdx.x * TM;

    float acc[2][4];
    #pragma unroll
    for (int i = 0; i < 2; ++i)
        #pragma unroll
        for (int j = 0; j < 4; ++j) acc[i][j] = 0.f;

    const int c4 = (tid & 31) << 2;    // float4 column within chunk: 0..124
    const int r0 = tid >> 5;           // staging row base: 0..7

    for (int k0 = 0; k0 < NH; k0 += HK) {
        // ---- stage x tile (TM x HK), coalesced 512B/row-half ----
        #pragma unroll
        for (int p = 0; p < 4; ++p) {
            const int r = r0 + (p << 3);
            const float4 v = *reinterpret_cast<const float4*>(
                x + (size_t)(t0 + r) * NH + k0 + c4);
            *reinterpret_cast<float4*>(&xs[r * PITCH + c4]) = v;
        }
        // ---- stage W tile (64 x HK); W is L2-resident (1 MB total) ----
        #pragma unroll
        for (int p = 0; p < 8; ++p) {
            const int r = r0 + (p << 3);
            const float4 v = *reinterpret_cast<const float4*>(
                w + (size_t)r * NH + k0 + c4);
            *reinterpret_cast<float4*>(&ws[r * PITCH + c4]) = v;
        }
        __syncthreads();

        // ---- inner: 2 tok x 4 exp per thread, strided (ty+16i, tx+16j) ----
        #pragma unroll 8
        for (int kk = 0; kk < HK; kk += 4) {
            const float4 xa = *reinterpret_cast<const float4*>(&xs[ty * PITCH + kk]);
            const float4 xb = *reinterpret_cast<const float4*>(&xs[(ty + 16) * PITCH + kk]);
            #pragma unroll
            for (int j = 0; j < 4; ++j) {
                const float4 wv = *reinterpret_cast<const float4*>(
                    &ws[(tx + (j << 4)) * PITCH + kk]);
                acc[0][j] = fmaf(xa.x, wv.x, acc[0][j]);
                acc[0][j] = fmaf(xa.y, wv.y, acc[0][j]);
                acc[0][j] = fmaf(xa.z, wv.z, acc[0][j]);
                acc[0][j] = fmaf(xa.w, wv.w, acc[0][j]);
                acc[1][j] = fmaf(xb.x, wv.x, acc[1][j]);
                acc[1][j] = fmaf(xb.y, wv.y, acc[1][j]);
                acc[1][j] = fmaf(xb.z, wv.z, acc[1][j]);
                acc[1][j] = fmaf(xb.w, wv.w, acc[1][j]);
            }
        }
        __syncthreads();
    }

    // ---- epilogue: logits -> LDS (reuse ws), then fused gating ----
    float* lg = ws;                    // 32 tokens x 64 experts, pitch 66
    #pragma unroll
    for (int i = 0; i < 2; ++i)
        #pragma unroll
        for (int j = 0; j < 4; ++j)
            lg[(ty + (i << 4)) * 66 + (tx + (j << 4))] = acc[i][j];
    __syncthreads();

    const int lane = tid & 63;         // lane == expert index
    const int wid  = tid >> 6;         // wave 0..3, each handles 8 tokens
    for (int tt = wid * 8; tt < wid * 8 + 8; ++tt) {
        const float logit = lg[tt * 66 + lane];

        // softmax over 64 experts (wave-wide)
        float m = logit;
        #pragma unroll
        for (int s = 32; s > 0; s >>= 1) m = fmaxf(m, __shfl_xor(m, s));
        const float ex = expf(logit - m);
        float sum = ex;
        #pragma unroll
        for (int s = 32; s > 0; s >>= 1) sum += __shfl_xor(sum, s);
        const float score = ex / sum;

        // per-group max (groups of 8 consecutive experts)
        float gm = score;
        #pragma unroll
        for (int s = 4; s > 0; s >>= 1) gm = fmaxf(gm, __shfl_xor(gm, s));
        const int g = lane >> 3;

        // rank of this lane's group among the 8 group-maxima (stable, desc)
        int grank = 0;
        #pragma unroll
        for (int gg = 0; gg < 8; ++gg) {
            const float o = __shfl(gm, gg << 3);
            grank += (o > gm) || (o == gm && gg < g);
        }
        const float masked = (grank < 3) ? score : 0.0f;

        // rank among all 64 masked scores (stable, desc) == output position
        int rank = 0;
        for (int ee = 0; ee < 64; ++ee) {
            const float o = __shfl(masked, ee);
            rank += (o > masked) || (o == masked && ee < lane);
        }
        if (rank < NTOPK) {
            const int t = t0 + tt;
            out_idx[t * NTOPK + rank] = (float)lane;   // float-encoded index
            out_w[t * NTOPK + rank]   = masked;
        }
    }
}

extern "C" void kernel_launch(void* const* d_in, const int* in_sizes, int n_in,
                              void* d_out, int out_size, void* d_ws, size_t ws_size,
                              hipStream_t stream) {
    const float* x = (const float*)d_in[0];
    const float* w = (const float*)d_in[1];
    const int T = in_sizes[0] / NH;            // 16384 tokens
    float* outf    = (float*)d_out;
    float* out_idx = outf;                     // first T*6: indices
    float* out_w   = outf + (size_t)T * NTOPK; // then  T*6: weights

    dim3 grid(T / TM), block(256);
    hipLaunchKernelGGL(moe_gate_kernel, grid, block, 0, stream,
                       x, w, out_idx, out_w);
}